// Round 1
// 483.934 us; speedup vs baseline: 1.0382x; 1.0382x over previous
//
#include <hip/hip_runtime.h>
#include <cstdint>
#include <cstddef>

#define NTOK 2048
#define DIMSZ 512
#define NH 8
#define DH 64

typedef __attribute__((ext_vector_type(8))) short bf16x8;
typedef __attribute__((ext_vector_type(4))) float f32x4;

__device__ __forceinline__ short f2bf(float f) {
  uint32_t u = __float_as_uint(f);
  u += 0x7fffu + ((u >> 16) & 1u);   // RNE
  return (short)(u >> 16);
}

// ---------------------------------------------------------------------------
// Kernel 1: fused triple projection GEMM, bf16 MFMA.  (unchanged this round)
//   P = epilogue(A @ W^T + b), A [2048,512] f32 row-major, W [512,512] f32.
//   blockIdx.z selects (query,Wq,bq)->Q(elu+1), (key,Wk,bk)->K(elu+1),
//   (value,Wv,bv)->V(raw).
//   Block 256 thr = 4 waves (2x2), block tile 128x128, BK=32, 16x16x32 MFMA.
// ---------------------------------------------------------------------------
#define LDSS 40  // padded LDS row stride in shorts (32 + 8)

__global__ __launch_bounds__(256) void proj_kernel(
    const float* __restrict__ query, const float* __restrict__ keyi,
    const float* __restrict__ val,
    const float* __restrict__ Wq, const float* __restrict__ bq,
    const float* __restrict__ Wk, const float* __restrict__ bk,
    const float* __restrict__ Wv, const float* __restrict__ bv,
    float* __restrict__ Qp, float* __restrict__ Kp, float* __restrict__ Vp)
{
  const float* A; const float* W; const float* bias; float* P; bool do_elu;
  if (blockIdx.z == 0)      { A = query; W = Wq; bias = bq; P = Qp; do_elu = true; }
  else if (blockIdx.z == 1) { A = keyi;  W = Wk; bias = bk; P = Kp; do_elu = true; }
  else                      { A = val;   W = Wv; bias = bv; P = Vp; do_elu = false; }

  __shared__ short Ash[128 * LDSS];
  __shared__ short Wsh[128 * LDSS];

  const int tid  = threadIdx.x;
  const int lane = tid & 63;
  const int wave = tid >> 6;
  const int l15  = lane & 15;
  const int quad = lane >> 4;
  const int waveM = wave >> 1;  // 0..1
  const int waveN = wave & 1;   // 0..1

  const int rowBase = blockIdx.y * 128;
  const int colBase = blockIdx.x * 128;

  f32x4 acc[4][4] = {};

  const int sRow = tid >> 3;        // 0..31
  const int sCol = (tid & 7) * 4;   // 0..28

  for (int k0 = 0; k0 < DIMSZ; k0 += 32) {
#pragma unroll
    for (int rr = 0; rr < 4; ++rr) {
      const int r = sRow + rr * 32;
      float4 va = *(const float4*)&A[(size_t)(rowBase + r) * DIMSZ + k0 + sCol];
      short4 sa = make_short4(f2bf(va.x), f2bf(va.y), f2bf(va.z), f2bf(va.w));
      *(short4*)&Ash[r * LDSS + sCol] = sa;
      float4 vw = *(const float4*)&W[(size_t)(colBase + r) * DIMSZ + k0 + sCol];
      short4 sw = make_short4(f2bf(vw.x), f2bf(vw.y), f2bf(vw.z), f2bf(vw.w));
      *(short4*)&Wsh[r * LDSS + sCol] = sw;
    }
    __syncthreads();

    bf16x8 afrag[4], bfrag[4];
#pragma unroll
    for (int mi = 0; mi < 4; ++mi) {
      const int m = waveM * 64 + mi * 16 + l15;
      afrag[mi] = *(const bf16x8*)&Ash[m * LDSS + quad * 8];
    }
#pragma unroll
    for (int ni = 0; ni < 4; ++ni) {
      const int n = waveN * 64 + ni * 16 + l15;
      bfrag[ni] = *(const bf16x8*)&Wsh[n * LDSS + quad * 8];
    }
#pragma unroll
    for (int mi = 0; mi < 4; ++mi)
#pragma unroll
      for (int ni = 0; ni < 4; ++ni)
        acc[mi][ni] = __builtin_amdgcn_mfma_f32_16x16x32_bf16(
            afrag[mi], bfrag[ni], acc[mi][ni], 0, 0, 0);
    __syncthreads();
  }

  // Epilogue: C/D layout col = lane&15, row = quad*4 + reg  [measured m89/m91]
#pragma unroll
  for (int mi = 0; mi < 4; ++mi) {
#pragma unroll
    for (int ni = 0; ni < 4; ++ni) {
      const int gcol = colBase + waveN * 64 + ni * 16 + l15;
      const float b = bias[gcol];
#pragma unroll
      for (int r = 0; r < 4; ++r) {
        const int grow = rowBase + waveM * 64 + mi * 16 + quad * 4 + r;
        float y = acc[mi][ni][r] + b;
        if (do_elu) y = (y > 0.0f) ? (y + 1.0f) : __expf(y);  // elu(y)+1
        P[(size_t)grow * DIMSZ + gcol] = y;
      }
    }
  }
}

// ---------------------------------------------------------------------------
// Kernel 2: stream Si, apply state update + output contraction.
//   One wave per (n,h). lane = g*16 + l:  l -> columns m=4l..4l+3,
//   g -> d in {g, g+4, ..., g+60}. Fully coalesced 1KiB/wave float4 Si
//   load+store.
//   R1 changes: (a) 8-deep load batches (reads issued back-to-back, then
//   stores) to raise outstanding reads and coarsen the R/W interleave;
//   (b) nontemporal load/store on the 540 MB streaming Si path so it does
//   not allocate in L2/L3 (use-once data, caches were just flushed by the
//   harness poison fill anyway).
// ---------------------------------------------------------------------------
__global__ __launch_bounds__(256) void stream_kernel(
    const float* __restrict__ Si, const float* __restrict__ Zi,
    const float* __restrict__ Qp, const float* __restrict__ Kp,
    const float* __restrict__ Vp,
    float* __restrict__ out, float* __restrict__ si_out,
    float* __restrict__ zi_out)
{
  const int wave = threadIdx.x >> 6;
  const int lane = threadIdx.x & 63;
  const int pair = blockIdx.x * 4 + wave;  // 0..16383 = n*8 + h
  const int n = pair >> 3;
  const int h = pair & 7;
  const int l = lane & 15;
  const int g = lane >> 4;

  const int    qkv_off = n * DIMSZ + h * DH;
  const int    zi_off  = pair * DH;
  const size_t si_off  = (size_t)pair * (DH * DH);

  const float4 q4  = *(const float4*)&Qp[qkv_off + l * 4];
  const float4 k4  = *(const float4*)&Kp[qkv_off + l * 4];
  const float4 v4  = *(const float4*)&Vp[qkv_off + l * 4];
  const float4 zi4 = *(const float4*)&Zi[zi_off + l * 4];

  f32x4 zin4;
  zin4.x = zi4.x + k4.x; zin4.y = zi4.y + k4.y;
  zin4.z = zi4.z + k4.z; zin4.w = zi4.w + k4.w;
  if (g == 0)
    __builtin_nontemporal_store(zin4, (f32x4*)&zi_out[zi_off + l * 4]);

  // z = 1/(Q . Zi_new + eps): partial over this lane's 4 elems, butterfly
  // over the 16-lane group (groups replicate the same data).
  float p = q4.x * zin4.x + q4.y * zin4.y + q4.z * zin4.z + q4.w * zin4.w;
  p += __shfl_xor(p, 1);
  p += __shfl_xor(p, 2);
  p += __shfl_xor(p, 4);
  p += __shfl_xor(p, 8);
  const float z = 1.0f / (p + 1e-6f);

  float qd[16], kd[16];
#pragma unroll
  for (int i = 0; i < 16; ++i) {
    const int d = i * 4 + g;
    qd[i] = Qp[qkv_off + d];
    kd[i] = Kp[qkv_off + d];
  }

  // Per-wave base of the Si panel: row d = g, cols l*4..l*4+3.
  // Iteration i advances d by 4 -> +256 floats.
  const float* sip = &Si[si_off + (size_t)g * DH + l * 4];
  float*       sop = &si_out[si_off + (size_t)g * DH + l * 4];

  float a0 = 0.f, a1 = 0.f, a2 = 0.f, a3 = 0.f;

#pragma unroll
  for (int c = 0; c < 16; c += 8) {
    f32x4 s[8];
#pragma unroll
    for (int j = 0; j < 8; ++j)
      s[j] = __builtin_nontemporal_load(
          (const f32x4*)(sip + (size_t)(c + j) * 256));
#pragma unroll
    for (int j = 0; j < 8; ++j) {
      const int i = c + j;
      f32x4 sn;
      sn.x = s[j].x + kd[i] * v4.x;
      sn.y = s[j].y + kd[i] * v4.y;
      sn.z = s[j].z + kd[i] * v4.z;
      sn.w = s[j].w + kd[i] * v4.w;
      __builtin_nontemporal_store(sn, (f32x4*)(sop + (size_t)(c + j) * 256));
      a0 += qd[i] * sn.x;
      a1 += qd[i] * sn.y;
      a2 += qd[i] * sn.z;
      a3 += qd[i] * sn.w;
    }
  }

  // reduce partial out over the 4 d-groups
  a0 += __shfl_xor(a0, 16); a0 += __shfl_xor(a0, 32);
  a1 += __shfl_xor(a1, 16); a1 += __shfl_xor(a1, 32);
  a2 += __shfl_xor(a2, 16); a2 += __shfl_xor(a2, 32);
  a3 += __shfl_xor(a3, 16); a3 += __shfl_xor(a3, 32);

  if (g == 0) {
    float4 o;
    o.x = a0 * z; o.y = a1 * z; o.z = a2 * z; o.w = a3 * z;
    *(float4*)&out[(size_t)n * DIMSZ + h * DH + l * 4] = o;
  }
}

// ---------------------------------------------------------------------------
extern "C" void kernel_launch(void* const* d_in, const int* in_sizes, int n_in,
                              void* d_out, int out_size, void* d_ws, size_t ws_size,
                              hipStream_t stream) {
  const float* query = (const float*)d_in[0];
  const float* key_  = (const float*)d_in[1];
  const float* value = (const float*)d_in[2];
  const float* Si    = (const float*)d_in[3];
  const float* Zi    = (const float*)d_in[4];
  const float* Wq    = (const float*)d_in[5];
  const float* bq    = (const float*)d_in[6];
  const float* Wk    = (const float*)d_in[7];
  const float* bk    = (const float*)d_in[8];
  const float* Wv    = (const float*)d_in[9];
  const float* bv    = (const float*)d_in[10];

  float* out    = (float*)d_out;
  float* si_out = out + (size_t)NTOK * DIMSZ;                   // 1,048,576
  float* zi_out = si_out + (size_t)NTOK * NH * DH * DH;         // +67,108,864

  float* Qp = (float*)d_ws;                 // 3 x 4 MB scratch
  float* Kp = Qp + (size_t)NTOK * DIMSZ;
  float* Vp = Kp + (size_t)NTOK * DIMSZ;

  dim3 g1(DIMSZ / 128, NTOK / 128, 3);      // 4 x 16 x 3 = 192 blocks
  proj_kernel<<<g1, 256, 0, stream>>>(query, key_, value, Wq, bq, Wk, bk,
                                      Wv, bv, Qp, Kp, Vp);

  stream_kernel<<<NTOK * NH / 4, 256, 0, stream>>>(Si, Zi, Qp, Kp, Vp,
                                                   out, si_out, zi_out);
}